// Round 1
// baseline (5655.495 us; speedup 1.0000x reference)
//
#include <hip/hip_runtime.h>
#include <math.h>

#define NB 32
#define NH 480
#define NW 640
#define HW (NH*NW)
#define BHW (NB*HW)
#define CAP 16384
#define TOPK 1024
#define NMS_T 0.3f

// ---------------------------------------------------------------- warp + mask
__global__ __launch_bounds__(256) void warp_kernel(
    const float* __restrict__ s2, const float* __restrict__ homo,
    float* __restrict__ w2, unsigned char* __restrict__ maskpre)
{
    int idx = blockIdx.x * 256 + threadIdx.x;
    if (idx >= BHW) return;
    int b = idx / HW;
    int rem = idx - b * HW;
    int y = rem / NW;
    int x = rem - y * NW;

    const float* h = homo + b * 9;
    float xf = (float)x, yf = (float)y;
    float w0 = h[0] * xf + h[1] * yf + h[2];
    float w1 = h[3] * xf + h[4] * yf + h[5];
    float w2v = h[6] * xf + h[7] * yf + h[8];
    float z = w2v + 1e-8f;
    float px = w0 / z;
    float py = w1 / z;

    float x0f = floorf(px), y0f = floorf(py);
    float wx = px - x0f, wy = py - y0f;
    int x0 = (int)x0f, y0 = (int)y0f;

    const float* img = s2 + (size_t)b * HW;
    bool vx0 = (x0 >= 0) && (x0 <= NW - 1);
    bool vx1 = (x0 + 1 >= 0) && (x0 + 1 <= NW - 1);
    bool vy0 = (y0 >= 0) && (y0 <= NH - 1);
    bool vy1 = (y0 + 1 >= 0) && (y0 + 1 <= NH - 1);

    float v00 = (vx0 && vy0) ? img[y0 * NW + x0] : 0.f;
    float v01 = (vx1 && vy0) ? img[y0 * NW + x0 + 1] : 0.f;
    float v10 = (vx0 && vy1) ? img[(y0 + 1) * NW + x0] : 0.f;
    float v11 = (vx1 && vy1) ? img[(y0 + 1) * NW + x0 + 1] : 0.f;

    float val = v00 * (1.f - wx) * (1.f - wy)
              + v01 * wx * (1.f - wy)
              + v10 * (1.f - wx) * wy
              + v11 * wx * wy;
    w2[idx] = val;

    // exact boolean equivalent of bilinear_sample(ones) > 0:
    // a corner contributes a strictly positive weight iff it is valid and its
    // weight factors (wx / wy where they appear) are > 0. (1-wx),(1-wy) > 0 always.
    bool m = (vx0 && vy0)
          || (wx > 0.f && vx1 && vy0)
          || (wy > 0.f && vx0 && vy1)
          || (wx > 0.f && wy > 0.f && vx1 && vy1);
    maskpre[idx] = m ? 1 : 0;
}

// ------------------------------------------- erode + mask multiply + norm sum
__global__ __launch_bounds__(256) void erode_mul_kernel(
    const unsigned char* __restrict__ mp, const float* __restrict__ s1,
    float* __restrict__ w2, float* __restrict__ s1m,
    float* __restrict__ mask_out, unsigned int* __restrict__ normbuck)
{
    int idx = blockIdx.x * 256 + threadIdx.x;
    if (idx >= BHW) return;
    int b = idx / HW;
    int rem = idx - b * HW;
    int y = rem / NW;
    int x = rem - y * NW;

    int em;
    if (x == 0 || x == NW - 1 || y == 0 || y == NH - 1) {
        em = 0; // zero border padding forces border pixels to 0
    } else {
        const unsigned char* q = mp + (size_t)b * HW + (y - 1) * NW + (x - 1);
        em = q[0] & q[1] & q[2]
           & q[NW] & q[NW + 1] & q[NW + 2]
           & q[2 * NW] & q[2 * NW + 1] & q[2 * NW + 2];
    }
    float emf = (float)em;
    mask_out[idx] = emf;
    s1m[idx] = s1[idx] * emf;
    w2[idx] = w2[idx] * emf;

    unsigned long long ball = __ballot(em != 0);
    if ((threadIdx.x & 63) == 0)
        atomicAdd(&normbuck[blockIdx.x & 63], (unsigned int)__popcll(ball));
}

// --------------------------------------------------- NMS + candidate collect
__global__ __launch_bounds__(256) void nms_kernel(
    const float* __restrict__ s1m, const float* __restrict__ w2m,
    unsigned long long* __restrict__ cand, int* __restrict__ cnt)
{
    int idx = blockIdx.x * 256 + threadIdx.x;
    if (idx >= BHW) return;
    int b = idx / HW;
    int rem = idx - b * HW;
    int y = rem / NW;
    int x = rem - y * NW;
    int y0 = max(y - 2, 0), y1 = min(y + 2, NH - 1);
    int x0 = max(x - 2, 0), x1 = min(x + 2, NW - 1);

    float c1 = s1m[idx];
    if (c1 > NMS_T) {
        const float* img = s1m + (size_t)b * HW;
        bool peak = true;
        for (int yy = y0; yy <= y1 && peak; ++yy)
            for (int xx = x0; xx <= x1; ++xx)
                if (img[yy * NW + xx] > c1) { peak = false; break; }
        if (peak) {
            unsigned long long key =
                ((unsigned long long)__float_as_uint(c1) << 32) |
                (unsigned long long)(0xFFFFFFFFu - (unsigned int)rem);
            int pos = atomicAdd(&cnt[b], 1);
            if (pos < CAP) cand[(size_t)b * CAP + pos] = key;
        }
    }
    float c2 = w2m[idx];
    if (c2 > NMS_T) {
        const float* img = w2m + (size_t)b * HW;
        bool peak = true;
        for (int yy = y0; yy <= y1 && peak; ++yy)
            for (int xx = x0; xx <= x1; ++xx)
                if (img[yy * NW + xx] > c2) { peak = false; break; }
        if (peak) {
            unsigned long long key =
                ((unsigned long long)__float_as_uint(c2) << 32) |
                (unsigned long long)(0xFFFFFFFFu - (unsigned int)rem);
            int pos = atomicAdd(&cnt[NB + b], 1);
            if (pos < CAP) cand[(size_t)(NB + b) * CAP + pos] = key;
        }
    }
}

// ------------------------------------------------- per-batch bitonic top-k
__global__ __launch_bounds__(1024) void sort_kernel(
    const unsigned long long* __restrict__ cand, const int* __restrict__ cnt,
    float* __restrict__ out, float* __restrict__ vals2, int* __restrict__ idx2)
{
    __shared__ unsigned long long keys[CAP]; // 128 KiB
    int blk = blockIdx.x;     // 0..63
    int field = blk >> 5;     // 0: score1 (kp out), 1: warped (scatter list)
    int b = blk & 31;
    int n = cnt[field * NB + b];
    if (n > CAP) n = CAP;
    const unsigned long long* src = cand + (size_t)(field * NB + b) * CAP;
    for (int i = threadIdx.x; i < CAP; i += 1024)
        keys[i] = (i < n) ? src[i] : 0ULL;
    __syncthreads();

    for (int k = 2; k <= CAP; k <<= 1) {
        for (int j = k >> 1; j > 0; j >>= 1) {
            for (int t = threadIdx.x; t < CAP / 2; t += 1024) {
                int i = ((t & ~(j - 1)) << 1) | (t & (j - 1));
                int ixj = i | j;
                bool descending = ((i & k) == 0);
                unsigned long long a = keys[i], c = keys[ixj];
                if ((a < c) == descending) { keys[i] = c; keys[ixj] = a; }
            }
            __syncthreads();
        }
    }

    int i = threadIdx.x; // exactly TOPK threads
    unsigned long long key = keys[i];
    unsigned int vb = (unsigned int)(key >> 32);
    int idx = (int)(0xFFFFFFFFu - (unsigned int)key);
    if (vb == 0) idx = i; // padding fallback (only if <1024 candidates)
    if (field == 0) {
        int y = idx / NW, x = idx - y * NW;
        out[1 + ((size_t)b * TOPK + i) * 2 + 0] = (float)y;
        out[1 + ((size_t)b * TOPK + i) * 2 + 1] = (float)x;
    } else {
        vals2[b * TOPK + i] = (vb == 0) ? 0.f : __uint_as_float(vb);
        idx2[b * TOPK + i] = idx;
    }
}

// ------------------------------------------------------- gaussian scatter
struct GaussK { float g[25]; };

__global__ __launch_bounds__(1024) void scatter_kernel(
    const float* __restrict__ vals2, const int* __restrict__ idx2,
    float* __restrict__ gt, GaussK gk)
{
    int b = blockIdx.x;
    int i = threadIdx.x;
    float v = vals2[b * TOPK + i];
    if (v == 0.f) return;
    int idx = idx2[b * TOPK + i];
    int y = idx / NW, x = idx - y * NW;
    float* img = gt + (size_t)b * HW;
#pragma unroll
    for (int dy = -2; dy <= 2; ++dy) {
        int yy = y + dy;
        if (yy < 0 || yy >= NH) continue;
#pragma unroll
        for (int dx = -2; dx <= 2; ++dx) {
            int xx = x + dx;
            if (xx < 0 || xx >= NW) continue;
            atomicAdd(&img[yy * NW + xx], v * gk.g[(dy + 2) * 5 + (dx + 2)]);
        }
    }
}

// ---------------------------------------------------------------- loss
__global__ __launch_bounds__(256) void loss_kernel(
    const float* __restrict__ a, const float* __restrict__ g,
    double* __restrict__ buck)
{
    double acc = 0.0;
    int stride = gridDim.x * 256;
    for (int i = blockIdx.x * 256 + threadIdx.x; i < BHW; i += stride) {
        float d = a[i] - g[i];
        float sq = d * d;
        acc += (double)sq;
    }
    for (int off = 32; off; off >>= 1) acc += __shfl_down(acc, off, 64);
    __shared__ double wsum[4];
    int lane = threadIdx.x & 63, wid = threadIdx.x >> 6;
    if (lane == 0) wsum[wid] = acc;
    __syncthreads();
    if (threadIdx.x == 0) {
        double t = wsum[0] + wsum[1] + wsum[2] + wsum[3];
        atomicAdd(&buck[blockIdx.x & 63], t);
    }
}

__global__ void final_kernel(const double* __restrict__ lbuck,
                             const unsigned int* __restrict__ nbuck,
                             float* __restrict__ out)
{
    if (threadIdx.x == 0) {
        double t = 0.0;
        unsigned long long nn = 0;
        for (int i = 0; i < 64; ++i) { t += lbuck[i]; nn += nbuck[i]; }
        out[0] = (float)(t / (double)nn);
    }
}

// ---------------------------------------------------------------- launch
extern "C" void kernel_launch(void* const* d_in, const int* in_sizes, int n_in,
                              void* d_out, int out_size, void* d_ws, size_t ws_size,
                              hipStream_t stream)
{
    const float* s1 = (const float*)d_in[0];
    const float* s2 = (const float*)d_in[1];
    const float* homo = (const float*)d_in[2];
    float* out = (float*)d_out;

    char* ws = (char*)d_ws;
    const size_t FB = (size_t)BHW * 4;               // 39,321,600 B
    float* s1m = (float*)ws;                         // [0, FB)
    float* w2 = (float*)(ws + FB);                   // [FB, 2FB) ; reused as gt
    unsigned char* mp = (unsigned char*)(ws + 2 * FB);           // + BHW bytes
    size_t off = 2 * FB + (size_t)BHW;               // 88,473,600
    unsigned long long* cand = (unsigned long long*)(ws + off);  // 2*32*CAP*8 = 8 MiB
    off += (size_t)2 * NB * CAP * 8;
    float* vals2 = (float*)(ws + off);  off += (size_t)NB * TOPK * 4;
    int* idx2 = (int*)(ws + off);       off += (size_t)NB * TOPK * 4;
    int* cnt = (int*)(ws + off);                     // 64 ints (256 B)
    unsigned int* nb = (unsigned int*)(ws + off + 256);  // 64 uints
    double* lb = (double*)(ws + off + 512);              // 64 doubles

    float* mask_out = out + 1 + (size_t)NB * TOPK * 2;

    // gaussian 5x5 sigma=2 coefficients, f64 math to match numpy
    GaussK gk;
    {
        double gg[5];
        for (int i = 0; i < 5; ++i) {
            double ax = (double)i - 2.0;
            gg[i] = ::exp(-(ax * ax) / 8.0);
        }
        double tot = 0.0;
        for (int i = 0; i < 5; ++i)
            for (int j = 0; j < 5; ++j) tot += gg[i] * gg[j];
        for (int i = 0; i < 5; ++i)
            for (int j = 0; j < 5; ++j)
                gk.g[i * 5 + j] = (float)(gg[i] * gg[j] / tot);
    }

    const int NBLK = (BHW + 255) / 256; // 38400 exactly

    hipMemsetAsync(cnt, 0, 1024, stream); // cnt + normbuck + lossbuck
    warp_kernel<<<NBLK, 256, 0, stream>>>(s2, homo, w2, mp);
    erode_mul_kernel<<<NBLK, 256, 0, stream>>>(mp, s1, w2, s1m, mask_out, nb);
    nms_kernel<<<NBLK, 256, 0, stream>>>(s1m, w2, cand, cnt);
    sort_kernel<<<64, 1024, 0, stream>>>(cand, cnt, out, vals2, idx2);
    hipMemsetAsync(w2, 0, FB, stream); // w2 buffer becomes gt map
    scatter_kernel<<<NB, TOPK, 0, stream>>>(vals2, idx2, w2, gk);
    loss_kernel<<<2048, 256, 0, stream>>>(s1m, w2, lb);
    final_kernel<<<1, 64, 0, stream>>>(lb, nb, out);
}

// Round 3
// 3192.584 us; speedup vs baseline: 1.7714x; 1.7714x over previous
//
#include <hip/hip_runtime.h>
#include <math.h>

#define NB 32
#define NH 480
#define NW 640
#define HW (NH*NW)
#define BHW (NB*HW)
#define CAP 16384
#define TOPK 1024
#define NMS_T 0.3f
#define TX 64
#define TY 16

// ---------------------------------------------------------------- warp + mask
__global__ __launch_bounds__(256) void warp_kernel(
    const float* __restrict__ s2, const float* __restrict__ homo,
    float* __restrict__ w2, unsigned char* __restrict__ maskpre)
{
    int idx = blockIdx.x * 256 + threadIdx.x;
    if (idx >= BHW) return;
    int b = idx / HW;
    int rem = idx - b * HW;
    int y = rem / NW;
    int x = rem - y * NW;

    const float* h = homo + b * 9;
    float xf = (float)x, yf = (float)y;
    float w0 = h[0] * xf + h[1] * yf + h[2];
    float w1 = h[3] * xf + h[4] * yf + h[5];
    float w2v = h[6] * xf + h[7] * yf + h[8];
    float z = w2v + 1e-8f;
    float px = w0 / z;
    float py = w1 / z;

    float x0f = floorf(px), y0f = floorf(py);
    float wx = px - x0f, wy = py - y0f;
    int x0 = (int)x0f, y0 = (int)y0f;

    const float* img = s2 + (size_t)b * HW;
    bool vx0 = (x0 >= 0) && (x0 <= NW - 1);
    bool vx1 = (x0 + 1 >= 0) && (x0 + 1 <= NW - 1);
    bool vy0 = (y0 >= 0) && (y0 <= NH - 1);
    bool vy1 = (y0 + 1 >= 0) && (y0 + 1 <= NH - 1);

    float v00 = (vx0 && vy0) ? img[y0 * NW + x0] : 0.f;
    float v01 = (vx1 && vy0) ? img[y0 * NW + x0 + 1] : 0.f;
    float v10 = (vx0 && vy1) ? img[(y0 + 1) * NW + x0] : 0.f;
    float v11 = (vx1 && vy1) ? img[(y0 + 1) * NW + x0 + 1] : 0.f;

    float val = v00 * (1.f - wx) * (1.f - wy)
              + v01 * wx * (1.f - wy)
              + v10 * (1.f - wx) * wy
              + v11 * wx * wy;
    w2[idx] = val;

    bool m = (vx0 && vy0)
          || (wx > 0.f && vx1 && vy0)
          || (wy > 0.f && vx0 && vy1)
          || (wx > 0.f && wy > 0.f && vx1 && vy1);
    maskpre[idx] = m ? 1 : 0;
}

// ------------------------------------------- erode + mask multiply + norm sum
__global__ __launch_bounds__(256) void erode_mul_kernel(
    const unsigned char* __restrict__ mp, const float* __restrict__ s1,
    float* __restrict__ w2, float* __restrict__ s1m,
    float* __restrict__ mask_out, unsigned int* __restrict__ normbuck)
{
    int idx = blockIdx.x * 256 + threadIdx.x;
    if (idx >= BHW) return;
    int b = idx / HW;
    int rem = idx - b * HW;
    int y = rem / NW;
    int x = rem - y * NW;

    int em;
    if (x == 0 || x == NW - 1 || y == 0 || y == NH - 1) {
        em = 0;
    } else {
        const unsigned char* q = mp + (size_t)b * HW + (y - 1) * NW + (x - 1);
        em = q[0] & q[1] & q[2]
           & q[NW] & q[NW + 1] & q[NW + 2]
           & q[2 * NW] & q[2 * NW + 1] & q[2 * NW + 2];
    }
    float emf = (float)em;
    mask_out[idx] = emf;
    s1m[idx] = s1[idx] * emf;
    w2[idx] = w2[idx] * emf;

    unsigned long long ball = __ballot(em != 0);
    if ((threadIdx.x & 63) == 0)
        atomicAdd(&normbuck[blockIdx.x & 63], (unsigned int)__popcll(ball));
}

// --------------------------------------- NMS via LDS-tiled dense 5x5 max
__global__ __launch_bounds__(256) void nms_kernel(
    const float* __restrict__ s1m, const float* __restrict__ w2m,
    unsigned long long* __restrict__ cand, int* __restrict__ cnt)
{
    __shared__ float tile[(TY + 4) * (TX + 4)]; // 68*20 floats = 5.4 KiB
    int tlin = blockIdx.x;          // 0..299 (10 x-tiles * 30 y-tiles)
    int b = blockIdx.y;
    int tyi = tlin / (NW / TX);
    int txi = tlin - tyi * (NW / TX);
    int bx0 = txi * TX, by0 = tyi * TY;
    int tid = threadIdx.x;
    int tx = tid & 63;
    int ty0 = (tid >> 6) * 4;

    for (int f = 0; f < 2; ++f) {
        const float* img = (f == 0 ? s1m : w2m) + (size_t)b * HW;
        if (f) __syncthreads(); // all reads of previous tile done
        for (int i = tid; i < (TY + 4) * (TX + 4); i += 256) {
            int ly = i / (TX + 4), lx = i - ly * (TX + 4);
            int gy = by0 + ly - 2, gx = bx0 + lx - 2;
            tile[i] = (gy >= 0 && gy < NH && gx >= 0 && gx < NW)
                    ? img[gy * NW + gx] : -1e30f;
        }
        __syncthreads();
        for (int r = 0; r < 4; ++r) {
            int ty = ty0 + r;
            float c = tile[(ty + 2) * (TX + 4) + tx + 2];
            if (c > NMS_T) {
                float m = -1e30f;
#pragma unroll
                for (int dy = 0; dy < 5; ++dy) {
#pragma unroll
                    for (int dx = 0; dx < 5; ++dx)
                        m = fmaxf(m, tile[(ty + dy) * (TX + 4) + tx + dx]);
                }
                if (m <= c) { // window max == c  <=>  (score == pooled)
                    int rem = (by0 + ty) * NW + bx0 + tx;
                    unsigned long long key =
                        ((unsigned long long)__float_as_uint(c) << 32) |
                        (unsigned long long)(0xFFFFFFFFu - (unsigned int)rem);
                    int pos = atomicAdd(&cnt[f * NB + b], 1);
                    if (pos < CAP) cand[(size_t)(f * NB + b) * CAP + pos] = key;
                }
            }
        }
    }
}

// ------------------------------------------------- per-batch bitonic top-k
__global__ __launch_bounds__(1024) void sort_kernel(
    const unsigned long long* __restrict__ cand, const int* __restrict__ cnt,
    float* __restrict__ out, float* __restrict__ vals2, int* __restrict__ idx2)
{
    __shared__ unsigned long long keys[CAP]; // 128 KiB
    int blk = blockIdx.x;     // 0..63
    int field = blk >> 5;     // 0: score1 (kp out), 1: warped (scatter list)
    int b = blk & 31;
    int n = cnt[field * NB + b];
    if (n > CAP) n = CAP;
    const unsigned long long* src = cand + (size_t)(field * NB + b) * CAP;
    for (int i = threadIdx.x; i < CAP; i += 1024)
        keys[i] = (i < n) ? src[i] : 0ULL;
    __syncthreads();

    for (int k = 2; k <= CAP; k <<= 1) {
        for (int j = k >> 1; j > 0; j >>= 1) {
            for (int t = threadIdx.x; t < CAP / 2; t += 1024) {
                int i = ((t & ~(j - 1)) << 1) | (t & (j - 1));
                int ixj = i | j;
                bool descending = ((i & k) == 0);
                unsigned long long a = keys[i], c = keys[ixj];
                if ((a < c) == descending) { keys[i] = c; keys[ixj] = a; }
            }
            __syncthreads();
        }
    }

    int i = threadIdx.x; // exactly TOPK threads
    unsigned long long key = keys[i];
    unsigned int vb = (unsigned int)(key >> 32);
    int idx = (int)(0xFFFFFFFFu - (unsigned int)key);
    if (vb == 0) idx = i; // padding fallback (only if <1024 candidates)
    if (field == 0) {
        int y = idx / NW, x = idx - y * NW;
        out[1 + ((size_t)b * TOPK + i) * 2 + 0] = (float)y;
        out[1 + ((size_t)b * TOPK + i) * 2 + 1] = (float)x;
    } else {
        vals2[b * TOPK + i] = (vb == 0) ? 0.f : __uint_as_float(vb);
        idx2[b * TOPK + i] = idx;
    }
}

// ------------------------------------------------------- gaussian scatter
struct GaussK { float g[25]; };

__global__ __launch_bounds__(1024) void scatter_kernel(
    const float* __restrict__ vals2, const int* __restrict__ idx2,
    float* __restrict__ gt, GaussK gk)
{
    int b = blockIdx.x;
    int i = threadIdx.x;
    float v = vals2[b * TOPK + i];
    if (v == 0.f) return;
    int idx = idx2[b * TOPK + i];
    int y = idx / NW, x = idx - y * NW;
    float* img = gt + (size_t)b * HW;
#pragma unroll
    for (int dy = -2; dy <= 2; ++dy) {
        int yy = y + dy;
        if (yy < 0 || yy >= NH) continue;
#pragma unroll
        for (int dx = -2; dx <= 2; ++dx) {
            int xx = x + dx;
            if (xx < 0 || xx >= NW) continue;
            atomicAdd(&img[yy * NW + xx], v * gk.g[(dy + 2) * 5 + (dx + 2)]);
        }
    }
}

// ---------------------------------------------------------------- loss
__global__ __launch_bounds__(256) void loss_kernel(
    const float* __restrict__ a, const float* __restrict__ g,
    double* __restrict__ buck)
{
    double acc = 0.0;
    int stride = gridDim.x * 256;
    for (int i = blockIdx.x * 256 + threadIdx.x; i < BHW; i += stride) {
        float d = a[i] - g[i];
        float sq = d * d;
        acc += (double)sq;
    }
    for (int off = 32; off; off >>= 1) acc += __shfl_down(acc, off, 64);
    __shared__ double wsum[4];
    int lane = threadIdx.x & 63, wid = threadIdx.x >> 6;
    if (lane == 0) wsum[wid] = acc;
    __syncthreads();
    if (threadIdx.x == 0) {
        double t = wsum[0] + wsum[1] + wsum[2] + wsum[3];
        atomicAdd(&buck[blockIdx.x & 63], t);
    }
}

__global__ void final_kernel(const double* __restrict__ lbuck,
                             const unsigned int* __restrict__ nbuck,
                             float* __restrict__ out)
{
    if (threadIdx.x == 0) {
        double t = 0.0;
        unsigned long long nn = 0;
        for (int i = 0; i < 64; ++i) { t += lbuck[i]; nn += nbuck[i]; }
        out[0] = (float)(t / (double)nn);
    }
}

// ---------------------------------------------------------------- launch
extern "C" void kernel_launch(void* const* d_in, const int* in_sizes, int n_in,
                              void* d_out, int out_size, void* d_ws, size_t ws_size,
                              hipStream_t stream)
{
    const float* s1 = (const float*)d_in[0];
    const float* s2 = (const float*)d_in[1];
    const float* homo = (const float*)d_in[2];
    float* out = (float*)d_out;

    char* ws = (char*)d_ws;
    const size_t FB = (size_t)BHW * 4;               // 39,321,600 B
    float* s1m = (float*)ws;                         // [0, FB)
    float* w2 = (float*)(ws + FB);                   // [FB, 2FB) ; reused as gt
    unsigned char* mp = (unsigned char*)(ws + 2 * FB);           // + BHW bytes
    size_t off = 2 * FB + (size_t)BHW;               // 88,473,600
    unsigned long long* cand = (unsigned long long*)(ws + off);  // 2*32*CAP*8 = 8 MiB
    off += (size_t)2 * NB * CAP * 8;
    float* vals2 = (float*)(ws + off);  off += (size_t)NB * TOPK * 4;
    int* idx2 = (int*)(ws + off);       off += (size_t)NB * TOPK * 4;
    int* cnt = (int*)(ws + off);                     // 64 ints (256 B)
    unsigned int* nb = (unsigned int*)(ws + off + 256);  // 64 uints
    double* lb = (double*)(ws + off + 512);              // 64 doubles

    float* mask_out = out + 1 + (size_t)NB * TOPK * 2;

    // gaussian 5x5 sigma=2 coefficients, f64 math to match numpy
    GaussK gk;
    {
        double gg[5];
        for (int i = 0; i < 5; ++i) {
            double ax = (double)i - 2.0;
            gg[i] = ::exp(-(ax * ax) / 8.0);
        }
        double tot = 0.0;
        for (int i = 0; i < 5; ++i)
            for (int j = 0; j < 5; ++j) tot += gg[i] * gg[j];
        for (int i = 0; i < 5; ++i)
            for (int j = 0; j < 5; ++j)
                gk.g[i * 5 + j] = (float)(gg[i] * gg[j] / tot);
    }

    const int NBLK = (BHW + 255) / 256; // 38400 exactly

    hipMemsetAsync(cnt, 0, 1024, stream); // cnt + normbuck + lossbuck
    warp_kernel<<<NBLK, 256, 0, stream>>>(s2, homo, w2, mp);
    erode_mul_kernel<<<NBLK, 256, 0, stream>>>(mp, s1, w2, s1m, mask_out, nb);
    nms_kernel<<<dim3(300, NB), 256, 0, stream>>>(s1m, w2, cand, cnt);
    sort_kernel<<<64, 1024, 0, stream>>>(cand, cnt, out, vals2, idx2);
    hipMemsetAsync(w2, 0, FB, stream); // w2 buffer becomes gt map
    scatter_kernel<<<NB, TOPK, 0, stream>>>(vals2, idx2, w2, gk);
    loss_kernel<<<2048, 256, 0, stream>>>(s1m, w2, lb);
    final_kernel<<<1, 64, 0, stream>>>(lb, nb, out);
}

// Round 4
// 480.748 us; speedup vs baseline: 11.7640x; 6.6409x over previous
//
#include <hip/hip_runtime.h>
#include <math.h>

#define NB 32
#define NH 480
#define NW 640
#define HW (NH*NW)
#define BHW (NB*HW)
#define CAP 16384
#define TOPK 1024
#define NMS_T 0.3f
#define TX 64
#define TY 16

// ---------------------------------------------------------------- warp + mask
__global__ __launch_bounds__(256) void warp_kernel(
    const float* __restrict__ s2, const float* __restrict__ homo,
    float* __restrict__ w2, unsigned char* __restrict__ maskpre)
{
    int idx = blockIdx.x * 256 + threadIdx.x;
    if (idx >= BHW) return;
    int b = idx / HW;
    int rem = idx - b * HW;
    int y = rem / NW;
    int x = rem - y * NW;

    const float* h = homo + b * 9;
    float xf = (float)x, yf = (float)y;
    float w0 = h[0] * xf + h[1] * yf + h[2];
    float w1 = h[3] * xf + h[4] * yf + h[5];
    float w2v = h[6] * xf + h[7] * yf + h[8];
    float z = w2v + 1e-8f;
    float px = w0 / z;
    float py = w1 / z;

    float x0f = floorf(px), y0f = floorf(py);
    float wx = px - x0f, wy = py - y0f;
    int x0 = (int)x0f, y0 = (int)y0f;

    const float* img = s2 + (size_t)b * HW;
    bool vx0 = (x0 >= 0) && (x0 <= NW - 1);
    bool vx1 = (x0 + 1 >= 0) && (x0 + 1 <= NW - 1);
    bool vy0 = (y0 >= 0) && (y0 <= NH - 1);
    bool vy1 = (y0 + 1 >= 0) && (y0 + 1 <= NH - 1);

    float v00 = (vx0 && vy0) ? img[y0 * NW + x0] : 0.f;
    float v01 = (vx1 && vy0) ? img[y0 * NW + x0 + 1] : 0.f;
    float v10 = (vx0 && vy1) ? img[(y0 + 1) * NW + x0] : 0.f;
    float v11 = (vx1 && vy1) ? img[(y0 + 1) * NW + x0 + 1] : 0.f;

    float val = v00 * (1.f - wx) * (1.f - wy)
              + v01 * wx * (1.f - wy)
              + v10 * (1.f - wx) * wy
              + v11 * wx * wy;
    w2[idx] = val;

    bool m = (vx0 && vy0)
          || (wx > 0.f && vx1 && vy0)
          || (wy > 0.f && vx0 && vy1)
          || (wx > 0.f && wy > 0.f && vx1 && vy1);
    maskpre[idx] = m ? 1 : 0;
}

// ------------------------------------------- erode + mask multiply + norm sum
// norm: block-level reduce, ONE atomic per block into a line-padded bucket
__global__ __launch_bounds__(256) void erode_mul_kernel(
    const unsigned char* __restrict__ mp, const float* __restrict__ s1,
    float* __restrict__ w2, float* __restrict__ s1m,
    float* __restrict__ mask_out, unsigned int* __restrict__ normbuck)
{
    int idx = blockIdx.x * 256 + threadIdx.x;
    int b = idx / HW;
    int rem = idx - b * HW;
    int y = rem / NW;
    int x = rem - y * NW;

    int em;
    if (x == 0 || x == NW - 1 || y == 0 || y == NH - 1) {
        em = 0;
    } else {
        const unsigned char* q = mp + (size_t)b * HW + (y - 1) * NW + (x - 1);
        em = q[0] & q[1] & q[2]
           & q[NW] & q[NW + 1] & q[NW + 2]
           & q[2 * NW] & q[2 * NW + 1] & q[2 * NW + 2];
    }
    float emf = (float)em;
    mask_out[idx] = emf;
    s1m[idx] = s1[idx] * emf;
    w2[idx] = w2[idx] * emf;

    unsigned long long ball = __ballot(em != 0);
    __shared__ unsigned int bs[4];
    int lane = threadIdx.x & 63, wv = threadIdx.x >> 6;
    if (lane == 0) bs[wv] = (unsigned int)__popcll(ball);
    __syncthreads();
    if (threadIdx.x == 0)
        atomicAdd(&normbuck[(blockIdx.x & 255) * 16], bs[0] + bs[1] + bs[2] + bs[3]);
}

// --------------------------------------- NMS: LDS-tiled dense 5x5 max,
// ballot compaction + one chunk-reserving atomic per block per field
__global__ __launch_bounds__(256) void nms_kernel(
    const float* __restrict__ s1m, const float* __restrict__ w2m,
    unsigned long long* __restrict__ cand, int* __restrict__ cntp)
{
    __shared__ float tile[(TY + 4) * (TX + 4)]; // 68*20 floats = 5.4 KiB
    __shared__ int wsum[4];
    __shared__ int base_sh;
    int tlin = blockIdx.x;          // 0..299
    int b = blockIdx.y;
    int tyi = tlin / (NW / TX);
    int txi = tlin - tyi * (NW / TX);
    int bx0 = txi * TX, by0 = tyi * TY;
    int tid = threadIdx.x;
    int lane = tid & 63;
    int wv = tid >> 6;
    int tx = lane;
    int ty0 = wv * 4;

    for (int f = 0; f < 2; ++f) {
        const float* img = (f == 0 ? s1m : w2m) + (size_t)b * HW;
        if (f) __syncthreads(); // reads of previous tile + wsum/base_sh done
        for (int i = tid; i < (TY + 4) * (TX + 4); i += 256) {
            int ly = i / (TX + 4), lx = i - ly * (TX + 4);
            int gy = by0 + ly - 2, gx = bx0 + lx - 2;
            tile[i] = (gy >= 0 && gy < NH && gx >= 0 && gx < NW)
                    ? img[gy * NW + gx] : -1e30f;
        }
        __syncthreads();

        unsigned long long keys[4];
        int slot[4];
        int wtot = 0;
#pragma unroll
        for (int r = 0; r < 4; ++r) {
            int ty = ty0 + r;
            float c = tile[(ty + 2) * (TX + 4) + tx + 2];
            bool pk = false;
            if (c > NMS_T) {
                float m = -1e30f;
#pragma unroll
                for (int dy = 0; dy < 5; ++dy)
#pragma unroll
                    for (int dx = 0; dx < 5; ++dx)
                        m = fmaxf(m, tile[(ty + dy) * (TX + 4) + tx + dx]);
                pk = (m <= c); // window max == c  <=>  (score == pooled)
            }
            unsigned long long bal = __ballot(pk);
            if (pk) {
                int rem = (by0 + ty) * NW + bx0 + tx;
                keys[r] = ((unsigned long long)__float_as_uint(c) << 32) |
                          (unsigned long long)(0xFFFFFFFFu - (unsigned int)rem);
                slot[r] = wtot + (int)__popcll(bal & ((1ull << lane) - 1ull));
            } else {
                slot[r] = -1;
            }
            wtot += (int)__popcll(bal);
        }
        if (lane == 0) wsum[wv] = wtot;
        __syncthreads();
        if (tid == 0) {
            int total = wsum[0] + wsum[1] + wsum[2] + wsum[3];
            base_sh = atomicAdd(&cntp[(f * NB + b) * 16], total);
        }
        __syncthreads();
        int wbase = base_sh;
        for (int i2 = 0; i2 < wv; ++i2) wbase += wsum[i2];
        unsigned long long* dst = cand + (size_t)(f * NB + b) * CAP;
#pragma unroll
        for (int r = 0; r < 4; ++r)
            if (slot[r] >= 0) {
                int p = wbase + slot[r];
                if (p < CAP) dst[p] = keys[r];
            }
    }
}

// ------------------------------------------------- per-batch bitonic top-k
__global__ __launch_bounds__(1024) void sort_kernel(
    const unsigned long long* __restrict__ cand, const int* __restrict__ cntp,
    float* __restrict__ out, float* __restrict__ vals2, int* __restrict__ idx2)
{
    __shared__ unsigned long long keys[CAP]; // 128 KiB
    int blk = blockIdx.x;     // 0..63
    int field = blk >> 5;     // 0: score1 (kp out), 1: warped (scatter list)
    int b = blk & 31;
    int n = cntp[(field * NB + b) * 16];
    if (n > CAP) n = CAP;
    const unsigned long long* src = cand + (size_t)(field * NB + b) * CAP;
    for (int i = threadIdx.x; i < CAP; i += 1024)
        keys[i] = (i < n) ? src[i] : 0ULL;
    __syncthreads();

    for (int k = 2; k <= CAP; k <<= 1) {
        for (int j = k >> 1; j > 0; j >>= 1) {
            for (int t = threadIdx.x; t < CAP / 2; t += 1024) {
                int i = ((t & ~(j - 1)) << 1) | (t & (j - 1));
                int ixj = i | j;
                bool descending = ((i & k) == 0);
                unsigned long long a = keys[i], c = keys[ixj];
                if ((a < c) == descending) { keys[i] = c; keys[ixj] = a; }
            }
            __syncthreads();
        }
    }

    int i = threadIdx.x; // exactly TOPK threads
    unsigned long long key = keys[i];
    unsigned int vb = (unsigned int)(key >> 32);
    int idx = (int)(0xFFFFFFFFu - (unsigned int)key);
    if (vb == 0) idx = i; // padding fallback (only if <1024 candidates)
    if (field == 0) {
        int y = idx / NW, x = idx - y * NW;
        out[1 + ((size_t)b * TOPK + i) * 2 + 0] = (float)y;
        out[1 + ((size_t)b * TOPK + i) * 2 + 1] = (float)x;
    } else {
        vals2[b * TOPK + i] = (vb == 0) ? 0.f : __uint_as_float(vb);
        idx2[b * TOPK + i] = idx;
    }
}

// ------------------------------------------------------- gaussian scatter
struct GaussK { float g[25]; };

__global__ __launch_bounds__(1024) void scatter_kernel(
    const float* __restrict__ vals2, const int* __restrict__ idx2,
    float* __restrict__ gt, GaussK gk)
{
    int b = blockIdx.x;
    int i = threadIdx.x;
    float v = vals2[b * TOPK + i];
    if (v == 0.f) return;
    int idx = idx2[b * TOPK + i];
    int y = idx / NW, x = idx - y * NW;
    float* img = gt + (size_t)b * HW;
#pragma unroll
    for (int dy = -2; dy <= 2; ++dy) {
        int yy = y + dy;
        if (yy < 0 || yy >= NH) continue;
#pragma unroll
        for (int dx = -2; dx <= 2; ++dx) {
            int xx = x + dx;
            if (xx < 0 || xx >= NW) continue;
            atomicAdd(&img[yy * NW + xx], v * gk.g[(dy + 2) * 5 + (dx + 2)]);
        }
    }
}

// ---------------------------------------------------------------- loss
__global__ __launch_bounds__(256) void loss_kernel(
    const float* __restrict__ a, const float* __restrict__ g,
    double* __restrict__ buck)
{
    double acc = 0.0;
    int stride = gridDim.x * 256;
    for (int i = blockIdx.x * 256 + threadIdx.x; i < BHW; i += stride) {
        float d = a[i] - g[i];
        float sq = d * d;
        acc += (double)sq;
    }
    for (int off = 32; off; off >>= 1) acc += __shfl_down(acc, off, 64);
    __shared__ double wsum[4];
    int lane = threadIdx.x & 63, wid = threadIdx.x >> 6;
    if (lane == 0) wsum[wid] = acc;
    __syncthreads();
    if (threadIdx.x == 0) {
        double t = wsum[0] + wsum[1] + wsum[2] + wsum[3];
        atomicAdd(&buck[(blockIdx.x & 63) * 8], t);
    }
}

__global__ __launch_bounds__(256) void final_kernel(
    const double* __restrict__ lbp, const unsigned int* __restrict__ nbp,
    float* __restrict__ out)
{
    __shared__ double ds[4];
    __shared__ unsigned int us[4];
    int tid = threadIdx.x, lane = tid & 63, wv = tid >> 6;
    unsigned int nv = nbp[tid * 16];
    double lv = (tid < 64) ? lbp[tid * 8] : 0.0;
    for (int off = 32; off; off >>= 1) {
        nv += __shfl_down(nv, off, 64);
        lv += __shfl_down(lv, off, 64);
    }
    if (lane == 0) { us[wv] = nv; ds[wv] = lv; }
    __syncthreads();
    if (tid == 0) {
        double t = ds[0] + ds[1] + ds[2] + ds[3];
        unsigned long long nn = (unsigned long long)us[0] + us[1] + us[2] + us[3];
        out[0] = (float)(t / (double)nn);
    }
}

// ---------------------------------------------------------------- launch
extern "C" void kernel_launch(void* const* d_in, const int* in_sizes, int n_in,
                              void* d_out, int out_size, void* d_ws, size_t ws_size,
                              hipStream_t stream)
{
    const float* s1 = (const float*)d_in[0];
    const float* s2 = (const float*)d_in[1];
    const float* homo = (const float*)d_in[2];
    float* out = (float*)d_out;

    char* ws = (char*)d_ws;
    const size_t FB = (size_t)BHW * 4;               // 39,321,600 B
    float* s1m = (float*)ws;                         // [0, FB)
    float* w2 = (float*)(ws + FB);                   // [FB, 2FB) ; reused as gt
    unsigned char* mp = (unsigned char*)(ws + 2 * FB);           // + BHW bytes
    size_t off = 2 * FB + (size_t)BHW;               // 88,473,600
    unsigned long long* cand = (unsigned long long*)(ws + off);  // 2*32*CAP*8 = 8 MiB
    off += (size_t)2 * NB * CAP * 8;
    float* vals2 = (float*)(ws + off);  off += (size_t)NB * TOPK * 4;
    int* idx2 = (int*)(ws + off);       off += (size_t)NB * TOPK * 4;
    // control block: all line-padded to kill same-line atomic contention
    int* cntp = (int*)(ws + off);                         // 64 * 64B  = 4 KiB
    unsigned int* nbp = (unsigned int*)(ws + off + 4096); // 256 * 64B = 16 KiB
    double* lbp = (double*)(ws + off + 20480);            // 64 * 64B  = 4 KiB

    float* mask_out = out + 1 + (size_t)NB * TOPK * 2;

    // gaussian 5x5 sigma=2 coefficients, f64 math to match numpy
    GaussK gk;
    {
        double gg[5];
        for (int i = 0; i < 5; ++i) {
            double ax = (double)i - 2.0;
            gg[i] = ::exp(-(ax * ax) / 8.0);
        }
        double tot = 0.0;
        for (int i = 0; i < 5; ++i)
            for (int j = 0; j < 5; ++j) tot += gg[i] * gg[j];
        for (int i = 0; i < 5; ++i)
            for (int j = 0; j < 5; ++j)
                gk.g[i * 5 + j] = (float)(gg[i] * gg[j] / tot);
    }

    const int NBLK = (BHW + 255) / 256; // 38400 exactly

    hipMemsetAsync(cntp, 0, 24576, stream); // cntp + nbp + lbp
    warp_kernel<<<NBLK, 256, 0, stream>>>(s2, homo, w2, mp);
    erode_mul_kernel<<<NBLK, 256, 0, stream>>>(mp, s1, w2, s1m, mask_out, nbp);
    nms_kernel<<<dim3(300, NB), 256, 0, stream>>>(s1m, w2, cand, cntp);
    sort_kernel<<<64, 1024, 0, stream>>>(cand, cntp, out, vals2, idx2);
    hipMemsetAsync(w2, 0, FB, stream); // w2 buffer becomes gt map
    scatter_kernel<<<NB, TOPK, 0, stream>>>(vals2, idx2, w2, gk);
    loss_kernel<<<2048, 256, 0, stream>>>(s1m, w2, lbp);
    final_kernel<<<1, 256, 0, stream>>>(lbp, nbp, out);
}

// Round 5
// 325.655 us; speedup vs baseline: 17.3665x; 1.4762x over previous
//
#include <hip/hip_runtime.h>
#include <math.h>

#define NB 32
#define NH 480
#define NW 640
#define HW (NH*NW)
#define BHW (NB*HW)
#define CAP 16384
#define TOPK 1024
#define NMS_T 0.3f
#define TX 64
#define TY 16

__device__ __forceinline__ bool analytic_mask(
    float xf, float yf, float h0, float h1, float h2, float h3, float h4,
    float h5, float h6, float h7, float h8)
{
    float w0 = h0 * xf + h1 * yf + h2;
    float w1 = h3 * xf + h4 * yf + h5;
    float wz = h6 * xf + h7 * yf + h8;
    float z = wz + 1e-8f;
    float px = w0 / z, py = w1 / z;
    float x0f = floorf(px), y0f = floorf(py);
    float wx = px - x0f, wy = py - y0f;
    int x0 = (int)x0f, y0 = (int)y0f;
    bool vx0 = (x0 >= 0) && (x0 <= NW - 1);
    bool vx1 = (x0 + 1 >= 0) && (x0 + 1 <= NW - 1);
    bool vy0 = (y0 >= 0) && (y0 <= NH - 1);
    bool vy1 = (y0 + 1 >= 0) && (y0 + 1 <= NH - 1);
    return (vx0 && vy0)
        || (wx > 0.f && vx1 && vy0)
        || (wy > 0.f && vx0 && vy1)
        || (wx > 0.f && wy > 0.f && vx1 && vy1);
}

// ---------------- fused warp + analytic-mask erode + mask multiply + norm ----
__global__ __launch_bounds__(256) void prep_kernel(
    const float* __restrict__ s1, const float* __restrict__ s2,
    const float* __restrict__ homo, float* __restrict__ s1m,
    float* __restrict__ w2m, float* __restrict__ mask_out,
    unsigned int* __restrict__ normbuck)
{
    __shared__ unsigned char msk[(TY + 2) * (TX + 2)]; // 18*66 = 1188 B
    __shared__ unsigned int ws[4];
    int tlin = blockIdx.x;          // 0..299
    int b = blockIdx.y;
    int tyi = tlin / (NW / TX);
    int txi = tlin - tyi * (NW / TX);
    int bx0 = txi * TX, by0 = tyi * TY;
    int tid = threadIdx.x;

    const float* h = homo + b * 9;
    float h0 = h[0], h1 = h[1], h2 = h[2], h3 = h[3], h4 = h[4];
    float h5 = h[5], h6 = h[6], h7 = h[7], h8 = h[8];

    // mask tile with 1-halo, computed analytically (no image reads)
    for (int i = tid; i < (TY + 2) * (TX + 2); i += 256) {
        int ly = i / (TX + 2), lx = i - ly * (TX + 2);
        int gy = by0 + ly - 1, gx = bx0 + lx - 1;
        int m = 0;
        if (gy >= 0 && gy < NH && gx >= 0 && gx < NW)
            m = analytic_mask((float)gx, (float)gy, h0, h1, h2, h3, h4, h5, h6, h7, h8) ? 1 : 0;
        msk[i] = (unsigned char)m;
    }
    __syncthreads();

    int tx = tid & 63, ty0v = (tid >> 6) * 4;
    const float* img2 = s2 + (size_t)b * HW;
    int cnt = 0;
#pragma unroll
    for (int r = 0; r < 4; ++r) {
        int ty = ty0v + r;
        int gx = bx0 + tx, gy = by0 + ty;
        // 3x3 erosion with zero border
        int em;
        if (gx == 0 || gx == NW - 1 || gy == 0 || gy == NH - 1) {
            em = 0;
        } else {
            const unsigned char* q = &msk[ty * (TX + 2) + tx];
            em = q[0] & q[1] & q[2]
               & q[TX + 2] & q[TX + 3] & q[TX + 4]
               & q[2 * (TX + 2)] & q[2 * (TX + 2) + 1] & q[2 * (TX + 2) + 2];
        }
        // warp value at own pixel (same float ops as reference path)
        float xf = (float)gx, yf = (float)gy;
        float w0 = h0 * xf + h1 * yf + h2;
        float w1 = h3 * xf + h4 * yf + h5;
        float wz = h6 * xf + h7 * yf + h8;
        float z = wz + 1e-8f;
        float px = w0 / z, py = w1 / z;
        float x0f = floorf(px), y0f = floorf(py);
        float wx = px - x0f, wy = py - y0f;
        int x0 = (int)x0f, y0 = (int)y0f;
        bool vx0 = (x0 >= 0) && (x0 <= NW - 1);
        bool vx1 = (x0 + 1 >= 0) && (x0 + 1 <= NW - 1);
        bool vy0 = (y0 >= 0) && (y0 <= NH - 1);
        bool vy1 = (y0 + 1 >= 0) && (y0 + 1 <= NH - 1);
        float v00 = (vx0 && vy0) ? img2[y0 * NW + x0] : 0.f;
        float v01 = (vx1 && vy0) ? img2[y0 * NW + x0 + 1] : 0.f;
        float v10 = (vx0 && vy1) ? img2[(y0 + 1) * NW + x0] : 0.f;
        float v11 = (vx1 && vy1) ? img2[(y0 + 1) * NW + x0 + 1] : 0.f;
        float val = v00 * (1.f - wx) * (1.f - wy)
                  + v01 * wx * (1.f - wy)
                  + v10 * (1.f - wx) * wy
                  + v11 * wx * wy;

        float emf = (float)em;
        int gidx = b * HW + gy * NW + gx;
        mask_out[gidx] = emf;
        s1m[gidx] = s1[gidx] * emf;
        w2m[gidx] = val * emf;
        cnt += em;
    }
    // block-reduce norm count, one padded atomic per block
    for (int off = 32; off; off >>= 1) cnt += __shfl_down(cnt, off, 64);
    int lane = tid & 63, wv = tid >> 6;
    if (lane == 0) ws[wv] = (unsigned int)cnt;
    __syncthreads();
    if (tid == 0) {
        int bid = blockIdx.y * 300 + blockIdx.x;
        atomicAdd(&normbuck[(bid & 255) * 16], ws[0] + ws[1] + ws[2] + ws[3]);
    }
}

// --------------------------- NMS: LDS-tiled dense 5x5 max, compacted append --
__global__ __launch_bounds__(256) void nms_kernel(
    const float* __restrict__ s1m, const float* __restrict__ w2m,
    unsigned long long* __restrict__ cand, int* __restrict__ cntp)
{
    __shared__ float tile[(TY + 4) * (TX + 4)];
    __shared__ int wsum[4];
    __shared__ int base_sh;
    int tlin = blockIdx.x;
    int b = blockIdx.y;
    int tyi = tlin / (NW / TX);
    int txi = tlin - tyi * (NW / TX);
    int bx0 = txi * TX, by0 = tyi * TY;
    int tid = threadIdx.x;
    int lane = tid & 63;
    int wv = tid >> 6;
    int tx = lane;
    int ty0 = wv * 4;

    for (int f = 0; f < 2; ++f) {
        const float* img = (f == 0 ? s1m : w2m) + (size_t)b * HW;
        if (f) __syncthreads();
        for (int i = tid; i < (TY + 4) * (TX + 4); i += 256) {
            int ly = i / (TX + 4), lx = i - ly * (TX + 4);
            int gy = by0 + ly - 2, gx = bx0 + lx - 2;
            tile[i] = (gy >= 0 && gy < NH && gx >= 0 && gx < NW)
                    ? img[gy * NW + gx] : -1e30f;
        }
        __syncthreads();

        unsigned long long keys[4];
        int slot[4];
        int wtot = 0;
#pragma unroll
        for (int r = 0; r < 4; ++r) {
            int ty = ty0 + r;
            float c = tile[(ty + 2) * (TX + 4) + tx + 2];
            bool pk = false;
            if (c > NMS_T) {
                float m = -1e30f;
#pragma unroll
                for (int dy = 0; dy < 5; ++dy)
#pragma unroll
                    for (int dx = 0; dx < 5; ++dx)
                        m = fmaxf(m, tile[(ty + dy) * (TX + 4) + tx + dx]);
                pk = (m <= c);
            }
            unsigned long long bal = __ballot(pk);
            if (pk) {
                int rem = (by0 + ty) * NW + bx0 + tx;
                keys[r] = ((unsigned long long)__float_as_uint(c) << 32) |
                          (unsigned long long)(0xFFFFFFFFu - (unsigned int)rem);
                slot[r] = wtot + (int)__popcll(bal & ((1ull << lane) - 1ull));
            } else {
                slot[r] = -1;
            }
            wtot += (int)__popcll(bal);
        }
        if (lane == 0) wsum[wv] = wtot;
        __syncthreads();
        if (tid == 0) {
            int total = wsum[0] + wsum[1] + wsum[2] + wsum[3];
            base_sh = atomicAdd(&cntp[(f * NB + b) * 16], total);
        }
        __syncthreads();
        int wbase = base_sh;
        for (int i2 = 0; i2 < wv; ++i2) wbase += wsum[i2];
        unsigned long long* dst = cand + (size_t)(f * NB + b) * CAP;
#pragma unroll
        for (int r = 0; r < 4; ++r)
            if (slot[r] >= 0) {
                int p = wbase + slot[r];
                if (p < CAP) dst[p] = keys[r];
            }
    }
}

// ------------- radix-select top-1024 + (field0: sort+kp out | field1: stamp) -
struct GaussK { float g[25]; };

__global__ __launch_bounds__(1024) void select_kernel(
    const unsigned long long* __restrict__ cand, const int* __restrict__ cntp,
    float* __restrict__ out, float* __restrict__ gt, GaussK gk)
{
    __shared__ unsigned long long keys[CAP];   // 128 KiB
    __shared__ unsigned int hist[2048];        // 8 KiB
    __shared__ unsigned int scn[2048];         // 8 KiB
    __shared__ unsigned long long sel[TOPK];   // 8 KiB
    __shared__ int sh_T, sh_need;
    __shared__ unsigned int selcnt;

    int blk = blockIdx.x;     // 0..63
    int field = blk >> 5;
    int b = blk & 31;
    int tid = threadIdx.x;
    int n = cntp[(field * NB + b) * 16];
    if (n > CAP) n = CAP;
    const unsigned long long* src = cand + (size_t)(field * NB + b) * CAP;
    for (int i = tid; i < n; i += 1024) keys[i] = src[i];
    for (int i = tid; i < TOPK; i += 1024) sel[i] = 0ULL;
    if (tid == 0) selcnt = 0;
    __syncthreads();

    unsigned long long kstar = 1ULL; // n<=TOPK: select all real keys
    if (n > TOPK) {
        unsigned long long prefix = 0ULL;
        int need = TOPK;
        const int shifts[6] = {53, 42, 31, 20, 9, 0};
        const int widths[6] = {11, 11, 11, 11, 11, 9};
        for (int p = 0; p < 6; ++p) {
            int sh = shifts[p], wdt = widths[p];
            int nb2 = 1 << wdt;
            unsigned int mk = (unsigned int)nb2 - 1u;
            int shp = (p == 0) ? 63 : (sh + wdt); // avoid shift-by-64 UB
            for (int i = tid; i < nb2; i += 1024) hist[i] = 0;
            __syncthreads();
            for (int i = tid; i < n; i += 1024) {
                unsigned long long k = keys[i];
                bool act = (p == 0) || ((k >> shp) == prefix);
                if (act) atomicAdd(&hist[(unsigned int)(k >> sh) & mk], 1u);
            }
            __syncthreads();
            // suffix sums: sp[i] = count of active keys with bin >= i
            unsigned int* sp = hist;
            unsigned int* dp = scn;
            for (int d = 1; d < nb2; d <<= 1) {
                for (int i = tid; i < nb2; i += 1024)
                    dp[i] = sp[i] + ((i + d < nb2) ? sp[i + d] : 0u);
                __syncthreads();
                unsigned int* t = sp; sp = dp; dp = t;
            }
            for (int i = tid; i < nb2; i += 1024) {
                unsigned int hi = sp[i];
                unsigned int ab = (i + 1 < nb2) ? sp[i + 1] : 0u;
                if (ab < (unsigned int)need && (unsigned int)need <= hi) {
                    sh_T = i;
                    sh_need = need - (int)ab;
                }
            }
            __syncthreads();
            prefix = (prefix << wdt) | (unsigned long long)sh_T;
            need = sh_need;
            __syncthreads();
        }
        kstar = prefix; // exact 1024th-largest key (keys unique)
    }

    // gather survivors (exactly min(n,TOPK) of them)
    for (int i = tid; i < n; i += 1024) {
        unsigned long long k = keys[i];
        if (k >= kstar) {
            unsigned int pos = atomicAdd(&selcnt, 1u);
            if (pos < TOPK) sel[pos] = k;
        }
    }
    __syncthreads();

    if (field == 0) {
        // order matters for kp output: bitonic sort 1024 (desc)
        for (int k2 = 2; k2 <= TOPK; k2 <<= 1) {
            for (int j = k2 >> 1; j > 0; j >>= 1) {
                int t = tid;
                if (t < TOPK / 2) {
                    int i = ((t & ~(j - 1)) << 1) | (t & (j - 1));
                    int ixj = i | j;
                    bool desc = ((i & k2) == 0);
                    unsigned long long a = sel[i], c = sel[ixj];
                    if ((a < c) == desc) { sel[i] = c; sel[ixj] = a; }
                }
                __syncthreads();
            }
        }
        if (tid < TOPK) {
            unsigned long long key = sel[tid];
            unsigned int vb = (unsigned int)(key >> 32);
            int idx = (int)(0xFFFFFFFFu - (unsigned int)key);
            if (vb == 0) idx = tid; // padding fallback
            int y = idx / NW, x = idx - y * NW;
            out[1 + ((size_t)b * TOPK + tid) * 2 + 0] = (float)y;
            out[1 + ((size_t)b * TOPK + tid) * 2 + 1] = (float)x;
        }
    } else {
        // order-independent: stamp gaussian directly
        if (tid < TOPK) {
            unsigned long long key = sel[tid];
            unsigned int vb = (unsigned int)(key >> 32);
            if (vb != 0) {
                float v = __uint_as_float(vb);
                int idx = (int)(0xFFFFFFFFu - (unsigned int)key);
                int y = idx / NW, x = idx - y * NW;
                float* img = gt + (size_t)b * HW;
#pragma unroll
                for (int dy = -2; dy <= 2; ++dy) {
                    int yy = y + dy;
                    if (yy < 0 || yy >= NH) continue;
#pragma unroll
                    for (int dx = -2; dx <= 2; ++dx) {
                        int xx = x + dx;
                        if (xx < 0 || xx >= NW) continue;
                        atomicAdd(&img[yy * NW + xx], v * gk.g[(dy + 2) * 5 + (dx + 2)]);
                    }
                }
            }
        }
    }
}

// ---------------------------------------------------------------- loss
__global__ __launch_bounds__(256) void loss_kernel(
    const float* __restrict__ a, const float* __restrict__ g,
    double* __restrict__ buck)
{
    double acc = 0.0;
    int stride = gridDim.x * 256;
    for (int i = blockIdx.x * 256 + threadIdx.x; i < BHW; i += stride) {
        float d = a[i] - g[i];
        float sq = d * d;
        acc += (double)sq;
    }
    for (int off = 32; off; off >>= 1) acc += __shfl_down(acc, off, 64);
    __shared__ double wsum[4];
    int lane = threadIdx.x & 63, wid = threadIdx.x >> 6;
    if (lane == 0) wsum[wid] = acc;
    __syncthreads();
    if (threadIdx.x == 0) {
        double t = wsum[0] + wsum[1] + wsum[2] + wsum[3];
        atomicAdd(&buck[(blockIdx.x & 63) * 8], t);
    }
}

__global__ __launch_bounds__(256) void final_kernel(
    const double* __restrict__ lbp, const unsigned int* __restrict__ nbp,
    float* __restrict__ out)
{
    __shared__ double ds[4];
    __shared__ unsigned int us[4];
    int tid = threadIdx.x, lane = tid & 63, wv = tid >> 6;
    unsigned int nv = nbp[tid * 16];
    double lv = (tid < 64) ? lbp[tid * 8] : 0.0;
    for (int off = 32; off; off >>= 1) {
        nv += __shfl_down(nv, off, 64);
        lv += __shfl_down(lv, off, 64);
    }
    if (lane == 0) { us[wv] = nv; ds[wv] = lv; }
    __syncthreads();
    if (tid == 0) {
        double t = ds[0] + ds[1] + ds[2] + ds[3];
        unsigned long long nn = (unsigned long long)us[0] + us[1] + us[2] + us[3];
        out[0] = (float)(t / (double)nn);
    }
}

// ---------------------------------------------------------------- launch
extern "C" void kernel_launch(void* const* d_in, const int* in_sizes, int n_in,
                              void* d_out, int out_size, void* d_ws, size_t ws_size,
                              hipStream_t stream)
{
    const float* s1 = (const float*)d_in[0];
    const float* s2 = (const float*)d_in[1];
    const float* homo = (const float*)d_in[2];
    float* out = (float*)d_out;

    char* ws = (char*)d_ws;
    const size_t FB = (size_t)BHW * 4;               // 39,321,600 B
    float* s1m = (float*)ws;                         // [0, FB)
    float* w2 = (float*)(ws + FB);                   // [FB, 2FB) ; reused as gt
    size_t off = 2 * FB;
    unsigned long long* cand = (unsigned long long*)(ws + off);  // 8 MiB
    off += (size_t)2 * NB * CAP * 8;
    // control block: all line-padded to kill same-line atomic contention
    int* cntp = (int*)(ws + off);                         // 64 * 64B  = 4 KiB
    unsigned int* nbp = (unsigned int*)(ws + off + 4096); // 256 * 64B = 16 KiB
    double* lbp = (double*)(ws + off + 20480);            // 64 * 64B  = 4 KiB

    float* mask_out = out + 1 + (size_t)NB * TOPK * 2;

    // gaussian 5x5 sigma=2 coefficients, f64 math to match numpy
    GaussK gk;
    {
        double gg[5];
        for (int i = 0; i < 5; ++i) {
            double ax = (double)i - 2.0;
            gg[i] = ::exp(-(ax * ax) / 8.0);
        }
        double tot = 0.0;
        for (int i = 0; i < 5; ++i)
            for (int j = 0; j < 5; ++j) tot += gg[i] * gg[j];
        for (int i = 0; i < 5; ++i)
            for (int j = 0; j < 5; ++j)
                gk.g[i * 5 + j] = (float)(gg[i] * gg[j] / tot);
    }

    hipMemsetAsync(cntp, 0, 24576, stream); // cntp + nbp + lbp
    prep_kernel<<<dim3(300, NB), 256, 0, stream>>>(s1, s2, homo, s1m, w2, mask_out, nbp);
    nms_kernel<<<dim3(300, NB), 256, 0, stream>>>(s1m, w2, cand, cntp);
    hipMemsetAsync(w2, 0, FB, stream); // w2m no longer needed -> becomes gt map
    select_kernel<<<64, 1024, 0, stream>>>(cand, cntp, out, w2, gk);
    loss_kernel<<<2048, 256, 0, stream>>>(s1m, w2, lbp);
    final_kernel<<<1, 256, 0, stream>>>(lbp, nbp, out);
}